// Round 8
// baseline (8365.509 us; speedup 1.0000x reference)
//
#include <hip/hip_runtime.h>
#include <hip/hip_fp16.h>

#define TCH 256
#define NCH 4

typedef __attribute__((ext_vector_type(8))) _Float16 half8;
typedef __attribute__((ext_vector_type(4))) float floatx4;

__device__ __forceinline__ float sigm(float x) {
  return __builtin_amdgcn_rcpf(1.f + __builtin_amdgcn_exp2f(x * -1.44269504f));
}
__device__ __forceinline__ float tanha(float x) {
  // tanh(x) = 1 - 2/(exp2(2x*log2e)+1); saturates correctly at +-inf
  return 1.f - 2.f * __builtin_amdgcn_rcpf(1.f + __builtin_amdgcn_exp2f(x * 2.88539009f));
}

// ---------------- GEMM: C[m,n] = A[m,:] . B[n,:]  (B row-major [N][K], fp32)
// A is f16 (or fp32 for MLP1), staged to LDS as f16; MFMA 16x16x32 f16.
// M = 32768 (chunk rows, m = b*TCH + t), tiles 128x128, BK=32.  (unchanged)
template<bool AF32, bool RELUB>
__global__ __launch_bounds__(256, 2) void gemm_k(
    const void* __restrict__ Ab, const float* __restrict__ Bw,
    const float* __restrict__ bias, __half* __restrict__ C,
    const int* __restrict__ length, int K, int KT, int N, int arst, int t0)
{
  int b = blockIdx.x >> 1;                  // 2 m-tiles (128 rows) per batch elem
  int tloc0 = (blockIdx.x & 1) << 7;
  if (t0 + tloc0 >= length[b]) return;      // whole tile beyond ragged length

  __shared__ half8 As[128][5];              // [row][k-group of 8], 40 f16/row (pad)
  __shared__ half8 Bs[128][5];

  int tid = threadIdx.x;
  int wave = tid >> 6, lane = tid & 63;
  int wm = (wave & 1) << 6, wn = (wave >> 1) << 6;
  int quad = lane >> 4, sub = lane & 15;
  int n0 = blockIdx.y << 7;

  floatx4 acc[4][4];
#pragma unroll
  for (int i = 0; i < 4; ++i)
#pragma unroll
    for (int j = 0; j < 4; ++j)
#pragma unroll
      for (int e = 0; e < 4; ++e) acc[i][j][e] = 0.f;

  size_t arowbase = (size_t)b * arst + tloc0;

  for (int kt = 0; kt < KT; ++kt) {
    int k0 = kt << 5;
#pragma unroll
    for (int pass = 0; pass < 2; ++pass) {
      int idx = tid + (pass << 8);
      int r = idx >> 2, c8 = (idx & 3) << 3;
      int kb = k0 + c8;
      // ---- A tile
      half8 v;
      if (AF32) {
        const float* src = (const float*)Ab + (arowbase + r) * K + kb;
        if (kb + 8 <= K) {
          float4 u0 = *(const float4*)(src);
          float4 u1 = *(const float4*)(src + 4);
          v[0] = (_Float16)u0.x; v[1] = (_Float16)u0.y; v[2] = (_Float16)u0.z; v[3] = (_Float16)u0.w;
          v[4] = (_Float16)u1.x; v[5] = (_Float16)u1.y; v[6] = (_Float16)u1.z; v[7] = (_Float16)u1.w;
        } else {
#pragma unroll
          for (int i = 0; i < 8; ++i) v[i] = (kb + i < K) ? (_Float16)src[i] : (_Float16)0.f;
        }
      } else {
        const __half* src = (const __half*)Ab + (arowbase + r) * K + kb;
        if (kb + 8 <= K) v = *(const half8*)src;
        else {
#pragma unroll
          for (int i = 0; i < 8; ++i) v[i] = (kb + i < K) ? *(const _Float16*)(src + i) : (_Float16)0.f;
        }
      }
      As[r][c8 >> 3] = v;
      // ---- B tile (always fp32 weights [N][K])
      const float* bsrc = Bw + (size_t)(n0 + r) * K + kb;
      half8 w;
      if (kb + 8 <= K) {
        float4 u0 = *(const float4*)(bsrc);
        float4 u1 = *(const float4*)(bsrc + 4);
        w[0] = (_Float16)u0.x; w[1] = (_Float16)u0.y; w[2] = (_Float16)u0.z; w[3] = (_Float16)u0.w;
        w[4] = (_Float16)u1.x; w[5] = (_Float16)u1.y; w[6] = (_Float16)u1.z; w[7] = (_Float16)u1.w;
      } else {
#pragma unroll
        for (int i = 0; i < 8; ++i) w[i] = (kb + i < K) ? (_Float16)bsrc[i] : (_Float16)0.f;
      }
      Bs[r][c8 >> 3] = w;
    }
    __syncthreads();
    half8 af[4], bfr[4];
#pragma unroll
    for (int i = 0; i < 4; ++i) {
      af[i] = As[wm + (i << 4) + sub][quad];
      bfr[i] = Bs[wn + (i << 4) + sub][quad];
    }
#pragma unroll
    for (int mt = 0; mt < 4; ++mt)
#pragma unroll
      for (int nt = 0; nt < 4; ++nt)
        acc[mt][nt] = __builtin_amdgcn_mfma_f32_16x16x32_f16(af[mt], bfr[nt], acc[mt][nt], 0, 0, 0);
    __syncthreads();
  }
  // epilogue: D layout col=lane&15 (n), row=quad*4+reg (m)  [m89-verified]
  size_t mrowbase = (size_t)blockIdx.x << 7;
#pragma unroll
  for (int nt = 0; nt < 4; ++nt) {
    int n = n0 + wn + (nt << 4) + sub;
    float bv = 0.f;
    if (RELUB) bv = bias[n];
#pragma unroll
    for (int mt = 0; mt < 4; ++mt) {
#pragma unroll
      for (int r4 = 0; r4 < 4; ++r4) {
        int m = wm + (mt << 4) + (quad << 2) + r4;
        float v = acc[mt][nt][r4] + bv;
        if (RELUB) v = fmaxf(v, 0.f);
        C[(mrowbase + m) * (size_t)N + n] = __float2half(v);
      }
    }
  }
}

// ---------------- pack W_hh [1024][256] f32 -> MFMA B-frag order f16 (quad).
// frag idx fi = (((qd*4+w)*4)+gt)*8+kc; lane (q=lane>>4, r=lane&15):
//   8 f16 = Whh[n = gt*256 + qd*64 + w*16 + r][k = kc*32 + q*8 + e]
__global__ void pack_whh(const float* __restrict__ whh, __half* __restrict__ wpk)
{
  int idx = blockIdx.x;           // 512 = 4*4*4*8
  int lane = threadIdx.x;
  int kc = idx & 7, gt = (idx >> 3) & 3, w = (idx >> 5) & 3, qd = (idx >> 7) & 3;
  int n = (gt << 8) + (qd << 6) + (w << 4) + (lane & 15);
  int k = (kc << 5) + ((lane >> 4) << 3);
  const float* src = whh + (size_t)n * 256 + k;
  half8 v;
#pragma unroll
  for (int e = 0; e < 8; ++e) v[e] = (_Float16)src[e];
  ((half8*)wpk)[((size_t)idx << 6) + lane] = v;
}

// ---------------- LSTM scan, MFMA version (v6: quad split).
// 32 WGs x 256 thr (4 waves, 1 wave/SIMD, __launch_bounds__(256,1) -> 512
// VGPR budget).  Round-7 counters: MFMA 16x16x32 f16 occupies ~20 cyc/SIMD,
// so v5b's 64 MFMA/SIMD/step = 1280 cyc was the floor.  Quad split spreads
// the same 512 MFMA/group-step over 2x the SIMDs: WG (g,qd) owns h-quarter
// qd (64 h-dims x 4 gates = 256 gate-rows, full K=256) for batches
// [16g,16g+16).  32 MFMA/wave/step, weights 128 regs/thread.
// Quad members bid = g + 8*qd land on ONE XCD under round-robin (bid%8=g).
// Exchange: v5b protocol generalized to 3 partners — each quarter publishes
// 512 tagged u64 (parity-dbuf); consumers validate 6 words/thread and
// scatter into 3 partner LDS regions.  Overwrite safety: we overwrite our
// tag-(t-1) parity only after validating ALL partners' tag t (proves they
// consumed t-1).  Spin bounded (diagnostic valve, never trips normally).
__global__ __launch_bounds__(256, 1) void scan_mf(
    const __half* __restrict__ xg, const __half* __restrict__ wpk,
    const float* __restrict__ bih, const float* __restrict__ bhh,
    __half* __restrict__ hout, __half* __restrict__ hsave,
    float* __restrict__ csave, unsigned long long* __restrict__ exch,
    const int* __restrict__ length, int t0)
{
  int bid = blockIdx.x;
  int g = bid & 7, qd = bid >> 3;               // quad {g, g+8, g+16, g+24}
  int sid = (g << 2) + qd;                      // state index
  int tid = threadIdx.x;
  int w = tid >> 6, lane = tid & 63;            // w in 0..3
  int q = lane >> 4, r = lane & 15;

  int maxlen = 0;
#pragma unroll
  for (int i = 0; i < 16; ++i) maxlen = max(maxlen, length[(g << 4) + i]);
  int tend = min(t0 + TCH, maxlen);
  if (t0 >= tend) return;                       // uniform across all 4 WGs of quad

  // 8 slices x 1KB: [0,2) own quarter kc, [2,4) partner1, [4,6) p2, [6,8) p3
  __shared__ __align__(16) unsigned short hfr[4096];

  int sp[3];
#pragma unroll
  for (int pi = 0; pi < 3; ++pi) sp[pi] = (g << 2) + ((qd + 1 + pi) & 3);

  // ---- resident B fragments: 128 regs. slot j: 0..1 own kc, 2..7 partners.
  half8 bf[4][8];
  {
    const half8* wpb = (const half8*)wpk;
#pragma unroll
    for (int gt = 0; gt < 4; ++gt)
#pragma unroll
      for (int j = 0; j < 8; ++j) {
        int kc = (((qd + (j >> 1)) & 3) << 1) + (j & 1);
        int fi = ((((qd << 2) + w) << 2) + gt) * 8 + kc;
        bf[gt][j] = wpb[((size_t)fi << 6) + lane];
      }
  }

  int hbase = (qd << 6) + (w << 4) + r;         // h-dim for this thread
  float bsum[4];
#pragma unroll
  for (int gt = 0; gt < 4; ++gt) bsum[gt] = bih[(gt << 8) + hbase] + bhh[(gt << 8) + hbase];

  // xg base pointers per acc row rr (batch m = 4q+rr)
  const __half* xb[4];
#pragma unroll
  for (int rr = 0; rr < 4; ++rr)
    xb[rr] = xg + ((size_t)((g << 4) + (q << 2) + rr) * TCH) * 1024 + hbase;

  float c0[4];
  if (t0 == 0) {
    ((uint4*)hfr)[tid] = uint4{0, 0, 0, 0};
    ((uint4*)hfr)[256 + tid] = uint4{0, 0, 0, 0};
#pragma unroll
    for (int rr = 0; rr < 4; ++rr) c0[rr] = 0.f;
  } else {
#pragma unroll
    for (int ii = 0; ii < 2; ++ii) {
      int idx = tid + (ii << 8);                // uint4 index in [0,512)
      uint4 v;
      if (idx < 128) {
        v = ((const uint4*)(hsave + ((size_t)sid << 10)))[idx];
      } else {
        int ri = (idx - 128) >> 7, wd = (idx - 128) & 127;
        v = ((const uint4*)(hsave + ((size_t)sp[ri] << 10)))[wd];
      }
      ((uint4*)hfr)[idx] = v;
    }
    int i = (w << 4) + r;
#pragma unroll
    for (int rr = 0; rr < 4; ++rr)
      c0[rr] = csave[((size_t)sid << 10) + (i << 4) + (q << 2) + rr];
  }
  __syncthreads();

  unsigned long long* exA = exch + ((size_t)sid << 10);   // 2 parities x 512
  const unsigned long long* exB[3];
#pragma unroll
  for (int pi = 0; pi < 3; ++pi) exB[pi] = exch + ((size_t)sp[pi] << 10);

  unsigned* h1w = (unsigned*)hfr;               // own region as u32 [0,512)
  // consumer: this thread owns words widx = 2*tid, 2*tid+1 of each partner buf
  int widx0 = tid << 1;
  int m_c = widx0 >> 5, p0 = widx0 & 31;
  unsigned cuoff = ((unsigned)(p0 >> 4) << 8) | ((unsigned)((p0 >> 2) & 3) << 6)
                 | ((unsigned)m_c << 2) | (unsigned)(p0 & 3);

  unsigned long long pw[6];

  for (int t = t0; t < tend; ++t) {
    int tl = t - t0;
    // own-quarter A frags (h_t)
    half8 afo[2];
#pragma unroll
    for (int s = 0; s < 2; ++s)
      afo[s] = *(const half8*)&hfr[((s << 6) + lane) << 3];

    // issue xg loads early (consumed at nonlinearity)
    __half xh[4][4];
#pragma unroll
    for (int gt = 0; gt < 4; ++gt)
#pragma unroll
      for (int rr = 0; rr < 4; ++rr)
        xh[gt][rr] = xb[rr][((size_t)tl << 10) + (gt << 8)];

    floatx4 acc[4];
#pragma unroll
    for (int gt = 0; gt < 4; ++gt)
#pragma unroll
      for (int e = 0; e < 4; ++e) acc[gt][e] = bsum[gt];

    // MFMA own quarter
#pragma unroll
    for (int s = 0; s < 2; ++s)
#pragma unroll
      for (int gt = 0; gt < 4; ++gt)
        acc[gt] = __builtin_amdgcn_mfma_f32_16x16x32_f16(afo[s], bf[gt][s], acc[gt], 0, 0, 0);

    // validate speculative partner words (tag t), scatter to partner regions
    if (tl > 0) {
      int guard = 0;
      for (;;) {
        bool ok = true;
#pragma unroll
        for (int j = 0; j < 6; ++j)
          if ((int)(unsigned)(pw[j] >> 32) != t) ok = false;
        if (ok || ++guard > (1 << 20)) break;
        __builtin_amdgcn_s_sleep(1);
#pragma unroll
        for (int ri = 0; ri < 3; ++ri) {
          const unsigned long long* pb = exB[ri] + ((size_t)(t & 1) << 9) + widx0;
          pw[(ri << 1)] = __hip_atomic_load(pb, __ATOMIC_RELAXED, __HIP_MEMORY_SCOPE_AGENT);
          pw[(ri << 1) + 1] = __hip_atomic_load(pb + 1, __ATOMIC_RELAXED, __HIP_MEMORY_SCOPE_AGENT);
        }
      }
#pragma unroll
      for (int ri = 0; ri < 3; ++ri)
        *(uint2*)&h1w[((1 + ri) << 9) + cuoff] =
            uint2{(unsigned)pw[(ri << 1)], (unsigned)pw[(ri << 1) + 1]};
    }
    __syncthreads();      // partner regions now h_t

    half8 afp[6];
#pragma unroll
    for (int s = 0; s < 6; ++s)
      afp[s] = *(const half8*)&hfr[(((2 + s) << 6) + lane) << 3];
#pragma unroll
    for (int s = 0; s < 6; ++s)
#pragma unroll
      for (int gt = 0; gt < 4; ++gt)
        acc[gt] = __builtin_amdgcn_mfma_f32_16x16x32_f16(afp[s], bf[gt][2 + s], acc[gt], 0, 0, 0);

    // nonlinearity + state update; pack h pairs in-register via shfl
    unsigned prv[4];
#pragma unroll
    for (int rr = 0; rr < 4; ++rr) {
      float iv = sigm(acc[0][rr] + __half2float(xh[0][rr]));
      float fv = sigm(acc[1][rr] + __half2float(xh[1][rr]));
      float gv = tanha(acc[2][rr] + __half2float(xh[2][rr]));
      float ov = sigm(acc[3][rr] + __half2float(xh[3][rr]));
      float c = fmaf(fv, c0[rr], iv * gv);
      c0[rr] = c;
      float hv = ov * tanha(c);
      __half hh = __float2half(hv);
      int m = (q << 2) + rr;
      hout[((size_t)(((g << 4) + m) * TCH + tl) << 8) + hbase] = hh;
      unsigned hu = (unsigned)__half_as_ushort(hh);
      unsigned ot = (unsigned)__shfl_xor((int)hu, 1);
      prv[rr] = (ot << 16) | hu;        // valid on even-r lanes
    }
    // even-r lanes: write own-frag region + publish to quad
    if (!(r & 1)) {
      unsigned long long tg = ((unsigned long long)(unsigned)(t + 1)) << 32;
      unsigned long long* dstb = exA + ((size_t)((t + 1) & 1) << 9);
#pragma unroll
      for (int rr = 0; rr < 4; ++rr) {
        int m = (q << 2) + rr;
        // own-frag u32 idx: s=w>>1, qq=2*(w&1)+(r>>3), ee=(r&7)>>1
        h1w[((w >> 1) << 8) + ((((w & 1) << 1) | (r >> 3)) << 6) + (m << 2) + ((r & 7) >> 1)] = prv[rr];
        int widx = (m << 5) + (w << 3) + (r >> 1);
        __hip_atomic_store(dstb + widx, tg | (unsigned long long)prv[rr],
                           __ATOMIC_RELAXED, __HIP_MEMORY_SCOPE_AGENT);
      }
    }
    // speculative partner loads for step t+1
    if (t + 1 < tend) {
#pragma unroll
      for (int ri = 0; ri < 3; ++ri) {
        const unsigned long long* pb = exB[ri] + ((size_t)((t + 1) & 1) << 9) + widx0;
        pw[(ri << 1)] = __hip_atomic_load(pb, __ATOMIC_RELAXED, __HIP_MEMORY_SCOPE_AGENT);
        pw[(ri << 1) + 1] = __hip_atomic_load(pb + 1, __ATOMIC_RELAXED, __HIP_MEMORY_SCOPE_AGENT);
      }
    }
    __syncthreads();      // own-frag region now h_{t+1}
  }

  // carry state across chunks (own region = 128 uint4)
  if (tid < 128)
    ((uint4*)(hsave + ((size_t)sid << 10)))[tid] = ((const uint4*)hfr)[tid];
  {
    int i = (w << 4) + r;
#pragma unroll
    for (int rr = 0; rr < 4; ++rr)
      csave[((size_t)sid << 10) + (i << 4) + (q << 2) + rr] = c0[rr];
  }
}

// ---------------- head: decision = h2 . Wd + bd, ragged-masked sum, final /len
__global__ __launch_bounds__(256, 2) void head_k(
    const __half* __restrict__ h2, const float* __restrict__ Wd,
    const float* __restrict__ bd, const int* __restrict__ length,
    float* __restrict__ dacc, float* __restrict__ out, int t0, int first, int last)
{
  int b = blockIdx.x, tid = threadIdx.x;
  int lane = tid & 63, wave = tid >> 6;
  int len = length[b];
  int tend = min(t0 + TCH, len);
  float4 w4 = *(const float4*)(Wd + (lane << 2));
  float wsum = 0.f;
  for (int t = t0 + wave; t < tend; t += 4) {
    const __half* hr = h2 + (((size_t)b * TCH) + (t - t0)) * 256 + (lane << 2);
    uint2 u = *(const uint2*)hr;
    __half2 p0 = __builtin_bit_cast(__half2, u.x);
    __half2 p1 = __builtin_bit_cast(__half2, u.y);
    float s = w4.x * __half2float(p0.x) + w4.y * __half2float(p0.y)
            + w4.z * __half2float(p1.x) + w4.w * __half2float(p1.y);
#pragma unroll
    for (int off = 32; off > 0; off >>= 1) s += __shfl_xor(s, off);
    wsum += s;    // s is full-wave sum, counted once via lane0 below
  }
  __shared__ float wred[4];
  if (lane == 0) wred[wave] = wsum;
  __syncthreads();
  if (tid == 0) {
    int cnt = tend - t0; if (cnt < 0) cnt = 0;
    float tot = wred[0] + wred[1] + wred[2] + wred[3] + bd[0] * (float)cnt;
    if (!first) tot += dacc[b];
    dacc[b] = tot;
    if (last) out[b] = tot / (float)len;
  }
}

extern "C" void kernel_launch(void* const* d_in, const int* in_sizes, int n_in,
                              void* d_out, int out_size, void* d_ws, size_t ws_size,
                              hipStream_t stream) {
  (void)in_sizes; (void)n_in; (void)out_size; (void)ws_size;
  const float* x    = (const float*)d_in[0];
  const int* length = (const int*)d_in[1];
  const float* W1   = (const float*)d_in[2];
  const float* b1   = (const float*)d_in[3];
  const float* W2   = (const float*)d_in[4];
  const float* b2   = (const float*)d_in[5];
  const float* wih[3] = {(const float*)d_in[6],  (const float*)d_in[10], (const float*)d_in[14]};
  const float* whh[3] = {(const float*)d_in[7],  (const float*)d_in[11], (const float*)d_in[15]};
  const float* bih[3] = {(const float*)d_in[8],  (const float*)d_in[12], (const float*)d_in[16]};
  const float* bhh[3] = {(const float*)d_in[9],  (const float*)d_in[13], (const float*)d_in[17]};
  const float* Wd   = (const float*)d_in[18];
  const float* bd   = (const float*)d_in[19];
  float* out = (float*)d_out;

  char* ws = (char*)d_ws;
  __half* XG    = (__half*)(ws);                     // 32768 x 1024 f16 = 64 MiB
  __half* FEAT2 = (__half*)(ws + 67108864);          // 32768 x 512  f16 = 32 MiB
  __half* FEAT1 = (__half*)(ws + 100663296);         // 32768 x 256  f16 = 16 MiB
  __half* HBUF  = FEAT1;                             // aliased: F1 dead before scan writes
  __half* WPK   = (__half*)(ws + 117440512);         // 3 x 512 KiB packed W_hh frags
  __half* HSV   = (__half*)(ws + 119013376);         // 3 x 64 KiB h state (frag order)
  float*  CSV   = (float*)(ws + 119209984);          // 3 x 128 KiB c state
  unsigned long long* EXC = (unsigned long long*)(ws + 119603200);  // 3 x 256 KiB exchange
  float* DACC   = (float*)(ws + 120389632);

  // pack recurrent weights into MFMA B-frag order (cheap, idempotent)
  for (int l = 0; l < 3; ++l)
    pack_whh<<<512, 64, 0, stream>>>(whh[l], WPK + (size_t)l * 262144);

  for (int c = 0; c < NCH; ++c) {
    int t0 = c * TCH;
    // MLP1: x[.,136] -> 256, relu
    gemm_k<true,  true ><<<dim3(256, 2), 256, 0, stream>>>(
        (const void*)(x + (size_t)t0 * 136), W1, b1, FEAT1, length, 136, 5, 256, 1024, t0);
    // MLP2: 256 -> 512, relu
    gemm_k<false, true ><<<dim3(256, 4), 256, 0, stream>>>(
        (const void*)FEAT1, W2, b2, FEAT2, length, 256, 8, 512, TCH, t0);
    // layer 0
    gemm_k<false, false><<<dim3(256, 8), 256, 0, stream>>>(
        (const void*)FEAT2, wih[0], nullptr, XG, length, 512, 16, 1024, TCH, t0);
    scan_mf<<<32, 256, 0, stream>>>(XG, WPK, bih[0], bhh[0], HBUF,
                                    HSV, CSV, EXC, length, t0);
    // layer 1
    gemm_k<false, false><<<dim3(256, 8), 256, 0, stream>>>(
        (const void*)HBUF, wih[1], nullptr, XG, length, 256, 8, 1024, TCH, t0);
    scan_mf<<<32, 256, 0, stream>>>(XG, WPK + 262144, bih[1], bhh[1], HBUF,
                                    HSV + 32768, CSV + 32768, EXC + 32768, length, t0);
    // layer 2
    gemm_k<false, false><<<dim3(256, 8), 256, 0, stream>>>(
        (const void*)HBUF, wih[2], nullptr, XG, length, 256, 8, 1024, TCH, t0);
    scan_mf<<<32, 256, 0, stream>>>(XG, WPK + 524288, bih[2], bhh[2], HBUF,
                                    HSV + 65536, CSV + 65536, EXC + 65536, length, t0);
    // head + ragged mean
    head_k<<<128, 256, 0, stream>>>(HBUF, Wd, bd, length, DACC, out, t0, c == 0, c == NCH - 1);
  }
}